// Round 8
// baseline (1728.140 us; speedup 1.0000x reference)
//
#include <hip/hip_runtime.h>

#define N_NODES 10000
#define IN_DIM 128
#define EDGE_DIM 64
#define HID_DIM 256
#define OUT_DIM 128
#define N_EDGES 640000

// Data contract (verified R6): fp32 buffers (values bf16-rounded), int32
// edge_index, fp32 output, atomic scatter into d_out.
// R8: kill the 2x atomic amplification. R5/R7 both pinned at ~543us with
// 164M atomic lane-ops = ~302 G/s = the TCC atomic-op wall. The hb split
// caused 2x atomics (both halves scatter all 128 cols) and 2x ea reads.
// This kernel: NO hb split. Full W1+W2 in LDS = 98304+65536 = 163,840 B
// (exactly 160 KiB, the whole CU's LDS -> 1 block/CU). No sMu strips:
// per-lane direct-to-register gather in B-frag layout (R3-PASSED pattern;
// complementary 16B instr pairs cover full lines; x is L2/L3-hot).
// GEMM1 = 16 hid tiles (96 MFMA), GEMM2 = 8 kb steps (64 MFMA), R3-proven
// shfl realign between them. Atomics halved: 82M ops, 128/edge, issued
// after next gather (never drained).

typedef __bf16 bf16x8 __attribute__((ext_vector_type(8)));
typedef float f32x4 __attribute__((ext_vector_type(4)));

// pre-rounded fp32 pair -> packed bf16 pair (exact: low mantissa bits are 0)
static __device__ __forceinline__ unsigned pk_pre(float lo, float hi) {
    return (__builtin_bit_cast(unsigned, lo) >> 16) |
           (__builtin_bit_cast(unsigned, hi) & 0xFFFF0000u);
}
// RNE f2bf for freshly computed values (h epilogue)
static __device__ __forceinline__ unsigned short f2bf(float f) {
    unsigned u = __builtin_bit_cast(unsigned, f);
    u = (u + 0x7fffu + ((u >> 16) & 1u)) >> 16;
    return (unsigned short)u;
}
static __device__ __forceinline__ float bf2f_lo(unsigned u) {
    return __builtin_bit_cast(float, u << 16);
}
static __device__ __forceinline__ float bf2f_hi(unsigned u) {
    return __builtin_bit_cast(float, u & 0xFFFF0000u);
}

__global__ void zero_kernel(float* __restrict__ out) {
    int t = blockIdx.x * 256 + threadIdx.x;
    if (t < 320000) ((float4*)out)[t] = make_float4(0.f, 0.f, 0.f, 0.f);
}

__global__ __launch_bounds__(512, 2) void gine_full(
    const int* __restrict__ ei,
    const float* __restrict__ x,
    const float* __restrict__ ea,
    const float* __restrict__ W1,
    const float* __restrict__ b1,
    const float* __restrict__ W2,
    const float* __restrict__ b2,
    float* __restrict__ out)
{
    // XOR-swizzled pad-free weight tiles (uint col ^= (row&7)<<2).
    // 98,304 + 65,536 = 163,840 B = exactly 160 KiB -> 1 block/CU.
    __shared__ __align__(16) unsigned sW1u[256 * 96];    // W1 full: [256 hid][96 k-pairs]
    __shared__ __align__(16) unsigned sW2u[128 * 128];   // W2 full: [128 out][128 k-pairs]

    const int tid = threadIdx.x;

    // ---- stage W1 full (swizzled; R3/R5/R7-verified scheme) ----
    for (int i = tid; i < 256 * 96; i += 512) {
        int r = i / 96, c2 = i - r * 96;
        const float* w = W1 + (size_t)r * 192 + c2 * 2;
        sW1u[r * 96 + (c2 ^ ((r & 7) << 2))] = pk_pre(w[0], w[1]);
    }
    // ---- stage W2 full ----
    for (int i = tid; i < 128 * 128; i += 512) {
        int r = i >> 7, c2 = i & 127;
        const float* w = W2 + (size_t)r * 256 + c2 * 2;
        sW2u[r * 128 + (c2 ^ ((r & 7) << 2))] = pk_pre(w[0], w[1]);
    }

    const int lane = tid & 63;
    const int e16  = lane & 15;
    const int q    = lane >> 4;
    const int wv   = tid >> 6;                   // 0..7
    const int rsw  = (e16 & 7) << 2;             // frag-read swizzle (rows = *16+e16)

    // ---- loop-invariant register state ----
    // b1 as packed bf16 (values pre-rounded): lane needs b1[mt*16+q*4+{0..3}]
    unsigned b1p0[16], b1p1[16];
    #pragma unroll
    for (int mt = 0; mt < 16; ++mt) {
        const float* bp = b1 + mt * 16 + q * 4;
        b1p0[mt] = pk_pre(bp[0], bp[1]);
        b1p1[mt] = pk_pre(bp[2], bp[3]);
    }
    float b2v[8];
    #pragma unroll
    for (int t = 0; t < 8; ++t) b2v[t] = b2[t * 16 + e16];

    __syncthreads();   // the only barrier: weights staged

    const int W = blockIdx.x * 8 + wv;           // 0..2047

    // ---- prologue: idx(g0) + per-lane gather(g0) in frag layout ----
    int g = W;
    int sidx = 0, didx = 0;
    if (lane < 16) {
        sidx = ei[g * 16 + lane];
        didx = ei[N_EDGES + g * 16 + lane];
    }
    float4 raw[12];
    {
        const int sr = __shfl(sidx, e16, 64);
        const float* xr = x + (size_t)sr * 128 + q * 8;
        #pragma unroll
        for (int ks = 0; ks < 4; ++ks) {
            raw[ks * 2 + 0] = *(const float4*)(xr + ks * 32);
            raw[ks * 2 + 1] = *(const float4*)(xr + ks * 32 + 4);
        }
        const float* er = ea + (size_t)(g * 16 + e16) * 64 + q * 8;
        #pragma unroll
        for (int t = 0; t < 2; ++t) {
            raw[8 + t * 2 + 0] = *(const float4*)(er + t * 32);
            raw[8 + t * 2 + 1] = *(const float4*)(er + t * 32 + 4);
        }
    }

    for (; g < 40000; g += 2048) {
        const int gn = (g + 2048 < 40000) ? g + 2048 : g;   // clamped prefetch

        // ---- idx(g+1): issue early ----
        int sidx_n = 0, didx_n = 0;
        if (lane < 16) {
            sidx_n = ei[gn * 16 + lane];
            didx_n = ei[N_EDGES + gn * 16 + lane];
        }

        // ---- GEMM1: h[16 edges][256 hid]; A=W1 (LDS), B=m (raw regs) ----
        // D: lane (e16,q) holds h[edge e16][hid mt*16+q*4+r]  [R3-verified]
        f32x4 acc1[16];
        #pragma unroll
        for (int t = 0; t < 16; ++t) acc1[t] = (f32x4){0.f, 0.f, 0.f, 0.f};
        #pragma unroll
        for (int ks = 0; ks < 6; ++ks) {
            int4 bi;
            bi.x = (int)pk_pre(raw[ks * 2].x, raw[ks * 2].y);
            bi.y = (int)pk_pre(raw[ks * 2].z, raw[ks * 2].w);
            bi.z = (int)pk_pre(raw[ks * 2 + 1].x, raw[ks * 2 + 1].y);
            bi.w = (int)pk_pre(raw[ks * 2 + 1].z, raw[ks * 2 + 1].w);
            bf16x8 bfrag = __builtin_bit_cast(bf16x8, bi);
            const int col = (ks * 16 + q * 4) ^ rsw;
            #pragma unroll
            for (int mt = 0; mt < 16; ++mt) {
                bf16x8 afrag = __builtin_bit_cast(bf16x8,
                    *(const int4*)&sW1u[(mt * 16 + e16) * 96 + col]);
                acc1[mt] = __builtin_amdgcn_mfma_f32_16x16x32_bf16(afrag, bfrag, acc1[mt], 0, 0, 0);
            }
        }

        // ---- epilogue: relu(+b1) -> packed bf16 pairs (pu0=r0|r1, pu1=r2|r3) ----
        unsigned pu0[16], pu1[16];
        #pragma unroll
        for (int mt = 0; mt < 16; ++mt) {
            float v0 = fmaxf(acc1[mt][0] + bf2f_lo(b1p0[mt]), 0.f);
            float v1 = fmaxf(acc1[mt][1] + bf2f_hi(b1p0[mt]), 0.f);
            float v2 = fmaxf(acc1[mt][2] + bf2f_lo(b1p1[mt]), 0.f);
            float v3 = fmaxf(acc1[mt][3] + bf2f_hi(b1p1[mt]), 0.f);
            pu0[mt] = (unsigned)f2bf(v0) | ((unsigned)f2bf(v1) << 16);
            pu1[mt] = (unsigned)f2bf(v2) | ((unsigned)f2bf(v3) << 16);
        }

        // ---- gather(g+1) NOW (older than this iter's atomics -> the vmcnt
        //      wait for raw next iter never drains the atomics) ----
        {
            const int sr = __shfl(sidx_n, e16, 64);
            const float* xr = x + (size_t)sr * 128 + q * 8;
            #pragma unroll
            for (int ks = 0; ks < 4; ++ks) {
                raw[ks * 2 + 0] = *(const float4*)(xr + ks * 32);
                raw[ks * 2 + 1] = *(const float4*)(xr + ks * 32 + 4);
            }
            const float* er = ea + (size_t)(gn * 16 + e16) * 64 + q * 8;
            #pragma unroll
            for (int t = 0; t < 2; ++t) {
                raw[8 + t * 2 + 0] = *(const float4*)(er + t * 32);
                raw[8 + t * 2 + 1] = *(const float4*)(er + t * 32 + 4);
            }
        }

        // ---- GEMM2 (operand-swapped): msg = h @ W2^T, k = 0..255 ----
        // A-frag (R3-PROVEN realign): lane (e16,q) holds h[e16][kb*32+q*8+j]
        //   j=0..3 from lane sa=(q&1)*32+e16, j=4..7 from sa+16;
        //   tile mt = 2kb + (q>>1) — TARGET's q, select AFTER shfl.
        // B-frag: lane holds W2[out=ot*16+e16][k=kb*32+q*8+j] from LDS.
        // D: lane (e16,q) holds msg[edge=q*4+r][out=ot*16+e16]
        f32x4 acc2[8];
        #pragma unroll
        for (int t = 0; t < 8; ++t) acc2[t] = (f32x4){0.f, 0.f, 0.f, 0.f};
        const int qh = q >> 1;
        const int sa = (q & 1) * 32 + e16;
        #pragma unroll
        for (int kb = 0; kb < 8; ++kb) {
            const int lo0 = (int)pu0[2 * kb],     lo1 = (int)pu1[2 * kb];
            const int hi0 = (int)pu0[2 * kb + 1], hi1 = (int)pu1[2 * kb + 1];
            int4 bi;
            {
                int a0 = __shfl(lo0, sa, 64),      a1 = __shfl(hi0, sa, 64);
                int b0 = __shfl(lo1, sa, 64),      b1_ = __shfl(hi1, sa, 64);
                int c0 = __shfl(lo0, sa + 16, 64), c1 = __shfl(hi0, sa + 16, 64);
                int d0 = __shfl(lo1, sa + 16, 64), d1 = __shfl(hi1, sa + 16, 64);
                bi.x = qh ? a1 : a0;
                bi.y = qh ? b1_ : b0;
                bi.z = qh ? c1 : c0;
                bi.w = qh ? d1 : d0;
            }
            bf16x8 hfrag = __builtin_bit_cast(bf16x8, bi);
            const int col = (kb * 16 + q * 4) ^ rsw;
            #pragma unroll
            for (int ot = 0; ot < 8; ++ot) {
                bf16x8 wfrag = __builtin_bit_cast(bf16x8,
                    *(const int4*)&sW2u[(ot * 16 + e16) * 128 + col]);
                acc2[ot] = __builtin_amdgcn_mfma_f32_16x16x32_bf16(hfrag, wfrag, acc2[ot], 0, 0, 0);
            }
        }

        // ---- scatter: 64B-contiguous atomic groups, never waited on ----
        int dr[4];
        #pragma unroll
        for (int r = 0; r < 4; ++r) dr[r] = __shfl(didx, q * 4 + r, 64);
        #pragma unroll
        for (int r = 0; r < 4; ++r) {
            float* ob = out + (size_t)dr[r] * 128 + e16;
            #pragma unroll
            for (int ot = 0; ot < 8; ++ot)
                unsafeAtomicAdd(ob + ot * 16, acc2[ot][r] + b2v[ot]);
        }

        sidx = sidx_n; didx = didx_n;
    }
}

extern "C" void kernel_launch(void* const* d_in, const int* in_sizes, int n_in,
                              void* d_out, int out_size, void* d_ws, size_t ws_size,
                              hipStream_t stream) {
    const float* x  = (const float*)d_in[0];
    const int*   ei = (const int*)d_in[1];
    const float* ea = (const float*)d_in[2];
    const float* W1 = (const float*)d_in[3];
    const float* b1 = (const float*)d_in[4];
    const float* W2 = (const float*)d_in[5];
    const float* b2 = (const float*)d_in[6];
    float* out = (float*)d_out;

    zero_kernel<<<1250, 256, 0, stream>>>(out);
    gine_full<<<256, 512, 0, stream>>>(ei, x, ea, W1, b1, W2, b2, out);
}